// Round 5
// baseline (406.374 us; speedup 1.0000x reference)
//
#include <hip/hip_runtime.h>

typedef __attribute__((ext_vector_type(8))) _Float16 f16x8;
typedef __attribute__((ext_vector_type(4))) float f32x4;

#define S_LEN 2048
#define DMODEL 1024
#define NHEAD 16
#define HD 64
#define QKV_LD 3072
#define BTOT 4
#define LOG2E 1.4426950408889634f

#define GLL16(g, l)                                              \
  __builtin_amdgcn_global_load_lds(                              \
      (const __attribute__((address_space(1))) void*)(g),        \
      (__attribute__((address_space(3))) void*)(l), 16, 0, 0)

#define MFMA16(a, b, c) __builtin_amdgcn_mfma_f32_16x16x32_f16(a, b, c, 0, 0, 0)

// ---------------- fp32 -> fp16 elementwise convert ----------------
__global__ __launch_bounds__(256) void cvt_f32_f16_k(const float* __restrict__ in,
                                                     _Float16* __restrict__ out, int n) {
  int i = (blockIdx.x * 256 + threadIdx.x) * 4;
  int stride = gridDim.x * 256 * 4;
  for (; i < n; i += stride) {
    float4 v = *(const float4*)(in + i);
    _Float16 h[4];
    h[0] = (_Float16)v.x; h[1] = (_Float16)v.y; h[2] = (_Float16)v.z; h[3] = (_Float16)v.w;
    *(uint2*)(out + i) = *(const uint2*)h;
  }
}

// ---------------- fp32 [K][N] -> fp16 [N][K] transpose-convert ----------------
__global__ __launch_bounds__(256) void transpose_cvt_k(const float* __restrict__ W,
                                                       _Float16* __restrict__ Wt,
                                                       int K, int N) {
  __shared__ float t[32][33];
  int n0 = blockIdx.x * 32, k0 = blockIdx.y * 32;
  int tx = threadIdx.x, ty = threadIdx.y;  // (32,8)
#pragma unroll
  for (int i = 0; i < 32; i += 8)
    t[ty + i][tx] = W[(size_t)(k0 + ty + i) * N + n0 + tx];
  __syncthreads();
#pragma unroll
  for (int i = 0; i < 32; i += 8)
    Wt[(size_t)(n0 + ty + i) * K + k0 + tx] = (_Float16)t[tx][ty + i];
}

// ---------------- fp16 GEMM: C[M][N] = A[M][K] * Bt[N][K]^T + bias ----------------
// m97 structure + group-of-8 L2 supertile swizzle.
template <int OUT_F32>
__global__ __launch_bounds__(256) void gemm_bt_k(const _Float16* __restrict__ A,
                                                 const _Float16* __restrict__ Bt,
                                                 const float* __restrict__ bias,
                                                 void* __restrict__ C,
                                                 int M, int N, int K) {
  __shared__ _Float16 As[128 * 32];
  __shared__ _Float16 Bs[128 * 32];
  const int tid = threadIdx.x;
  const int wid = tid >> 6, lane = tid & 63;
  const int quad = lane >> 4, l16 = lane & 15;
  const int wr = wid >> 1, wc = wid & 1;

  const int lin = blockIdx.y * gridDim.x + blockIdx.x;
  const int width = 8 * gridDim.x;
  const int group = lin / width;
  const int pm = group * 8 + (lin % width) % 8;
  const int pn = (lin % width) / 8;
  const int tm = pm * 128, tn = pn * 128;

  const int sr = tid >> 2;
  const int scc = (tid & 3) * 8;
  const _Float16* Ag = A + (size_t)(tm + sr) * K + scc;
  const _Float16* Bg = Bt + (size_t)(tn + sr) * K + scc;
  _Float16* AsW = &As[wid * 512];
  _Float16* BsW = &Bs[wid * 512];

  f32x4 acc[4][4] = {};

  for (int k0 = 0; k0 < K; k0 += 32) {
    __syncthreads();
    GLL16(Ag + k0, AsW);
    GLL16(Ag + k0 + (size_t)64 * K, AsW + 2048);
    GLL16(Bg + k0, BsW);
    GLL16(Bg + k0 + (size_t)64 * K, BsW + 2048);
    __syncthreads();

    f16x8 af[4], bf[4];
#pragma unroll
    for (int mt = 0; mt < 4; mt++)
      af[mt] = *(const f16x8*)&As[(wr * 64 + mt * 16 + l16) * 32 + quad * 8];
#pragma unroll
    for (int nt = 0; nt < 4; nt++)
      bf[nt] = *(const f16x8*)&Bs[(wc * 64 + nt * 16 + l16) * 32 + quad * 8];
#pragma unroll
    for (int mt = 0; mt < 4; mt++)
#pragma unroll
      for (int nt = 0; nt < 4; nt++)
        acc[mt][nt] = MFMA16(af[mt], bf[nt], acc[mt][nt]);
  }

#pragma unroll
  for (int nt = 0; nt < 4; nt++) {
    int col = tn + wc * 64 + nt * 16 + l16;
    float bv = bias[col];
#pragma unroll
    for (int mt = 0; mt < 4; mt++) {
      int row = tm + wr * 64 + mt * 16 + quad * 4;
#pragma unroll
      for (int r = 0; r < 4; r++) {
        float v = acc[mt][nt][r] + bv;
        if (OUT_F32)
          ((float*)C)[(size_t)(row + r) * N + col] = v;
        else
          ((_Float16*)C)[(size_t)(row + r) * N + col] = (_Float16)v;
      }
    }
  }
}

// ---------------- fused causal flash attention: paired q-tiles ----------------
// Block handles q-tiles p (A) and 15-p (B) of the same (b,h): uniform 34
// compute-units/block; each staged K/V tile feeds both. XOR-swizzled K/V^T LDS
// (conflict-free b128 fragment reads). Double-buffered register-staged K/V.
__global__ __launch_bounds__(256, 2) void attn_k(const _Float16* __restrict__ qkv,
                                                 _Float16* __restrict__ out) {
  __shared__ _Float16 Ks[2][4096];   // [k 64][d 64], chunk-swizzled, 16 KB
  __shared__ _Float16 VTs[2][4096];  // [d 64][k 64], chunk-swizzled, 16 KB
  __shared__ _Float16 Ps[8][2304];   // per-wave 32x72: [wid]=A, [wid+4]=B, 36 KB

  const int tid = threadIdx.x, wid = tid >> 6, lane = tid & 63;
  const int quad = lane >> 4, l16 = lane & 15;
  const int p = blockIdx.x;  // 0..7
  const int qtA = p * 128, qtB = (15 - p) * 128;
  const int bh = blockIdx.y, b = bh >> 4, h = bh & 15;
  const _Float16* base = qkv + (size_t)b * S_LEN * QKV_LD + h * HD;

  // ---- Q fragments in registers (B-operand layout), pre-scaled ----
  f16x8 bqA[2][2], bqB[2][2];  // [nt][ks]
  {
    const _Float16 qs = (_Float16)(0.125f * LOG2E);
#pragma unroll
    for (int nt = 0; nt < 2; nt++)
#pragma unroll
      for (int ks = 0; ks < 2; ks++) {
        union { uint4 u; f16x8 h; } va, vb;
        va.u = *(const uint4*)(base + (size_t)(qtA + wid * 32 + nt * 16 + l16) * QKV_LD +
                               ks * 32 + quad * 8);
        vb.u = *(const uint4*)(base + (size_t)(qtB + wid * 32 + nt * 16 + l16) * QKV_LD +
                               ks * 32 + quad * 8);
        bqA[nt][ks] = va.h * qs;
        bqB[nt][ks] = vb.h * qs;
      }
  }

  // K staging: thread covers rows tid>>3 and +32, cols (tid&7)*8, swizzled chunk
  const int krow = tid >> 3;
  const int kch = ((tid & 7) ^ (krow & 7)) << 3;  // (krow+32)&7 == krow&7
  const _Float16* Kg = base + DMODEL + (size_t)krow * QKV_LD + (tid & 7) * 8;
  // V staging (register transpose): rows 2kp,2kp+1, cols dbase..+7
  const int kp = tid & 31, dbase = (tid >> 5) * 8;
  const _Float16* Vg = base + 2 * DMODEL + (size_t)(2 * kp) * QKV_LD + dbase;

  auto stage_KV = [&](int bufi, uint4 k0, uint4 k1, uint4 v0, uint4 v1) {
    *(uint4*)&Ks[bufi][krow * 64 + kch] = k0;
    *(uint4*)&Ks[bufi][(krow + 32) * 64 + kch] = k1;
    union { uint4 u; _Float16 h[8]; } a, c;
    a.u = v0; c.u = v1;
    uint* VT32 = (uint*)VTs[bufi];
#pragma unroll
    for (int i = 0; i < 8; i++) {
      int d = dbase + i;
      union { _Float16 h[2]; uint u; } w;
      w.h[0] = a.h[i]; w.h[1] = c.h[i];
      VT32[d * 32 + (((kp >> 2) ^ (d & 7)) << 2) + (kp & 3)] = w.u;
    }
  };

  auto softmax_store = [&](f32x4 (&sc)[4][2], float (&m_i)[2], float (&l_i)[2],
                           float (&alpha)[2], int qmin_w, _Float16* PsW, int k0g) {
    const bool need_mask = (k0g + 63 > qmin_w);
#pragma unroll
    for (int nt = 0; nt < 2; nt++) {
      const int qg = qmin_w + nt * 16 + l16;
      float s[16];
#pragma unroll
      for (int mt = 0; mt < 4; mt++)
#pragma unroll
        for (int r = 0; r < 4; r++) {
          float v = sc[mt][nt][r];
          if (need_mask) {
            int kg = k0g + mt * 16 + quad * 4 + r;
            v = (kg <= qg) ? v : -3.0e38f;
          }
          s[mt * 4 + r] = v;
        }
      float mx = s[0];
#pragma unroll
      for (int i = 1; i < 16; i++) mx = fmaxf(mx, s[i]);
      mx = fmaxf(mx, __shfl_xor(mx, 16, 64));
      mx = fmaxf(mx, __shfl_xor(mx, 32, 64));
      float mnew = fmaxf(m_i[nt], mx);
      alpha[nt] = __builtin_amdgcn_exp2f(m_i[nt] - mnew);
      m_i[nt] = mnew;
      float rs = 0.f;
      _Float16 ph[16];
#pragma unroll
      for (int i = 0; i < 16; i++) {
        float pv = __builtin_amdgcn_exp2f(s[i] - mnew);
        rs += pv;
        ph[i] = (_Float16)pv;
      }
      rs += __shfl_xor(rs, 16, 64);
      rs += __shfl_xor(rs, 32, 64);
      l_i[nt] = l_i[nt] * alpha[nt] + rs;
#pragma unroll
      for (int mt = 0; mt < 4; mt++)
        *(uint2*)&PsW[(nt * 16 + l16) * 72 + mt * 16 + quad * 4] = *(uint2*)&ph[mt * 4];
    }
  };

  float mA[2] = {-1e30f, -1e30f}, lA[2] = {0.f, 0.f};
  float mB[2] = {-1e30f, -1e30f}, lB[2] = {0.f, 0.f};
  f32x4 oA[4][2] = {}, oB[4][2] = {};

  const int qminA = qtA + wid * 32, qminB = qtB + wid * 32;
  const int ntA = 2 * p + 2;   // A's K-tile count
  const int nj = 32 - 2 * p;   // B's K-tile count (loop bound), nj >= ntA

  // ---- prologue: stage tile 0 ----
  {
    uint4 k0 = *(const uint4*)(Kg);
    uint4 k1 = *(const uint4*)(Kg + (size_t)32 * QKV_LD);
    uint4 v0 = *(const uint4*)(Vg);
    uint4 v1 = *(const uint4*)(Vg + QKV_LD);
    stage_KV(0, k0, k1, v0, v1);
  }
  __syncthreads();

  for (int j = 0; j < nj; j++) {
    const int cur = j & 1, nxt = cur ^ 1;
    const int k0g = j * 64;
    const bool pf = (j + 1 < nj);
    uint4 pk0, pk1, pv0, pv1;
    if (pf) {
      const int kn = k0g + 64;
      pk0 = *(const uint4*)(Kg + (size_t)kn * QKV_LD);
      pk1 = *(const uint4*)(Kg + (size_t)(kn + 32) * QKV_LD);
      pv0 = *(const uint4*)(Vg + (size_t)kn * QKV_LD);
      pv1 = *(const uint4*)(Vg + (size_t)(kn + 1) * QKV_LD);
    }

    const bool actA = (j < ntA);

    // ---- scores: shared K fragments feed both q-tiles ----
    f32x4 scA[4][2] = {}, scB[4][2] = {};
#pragma unroll
    for (int ks = 0; ks < 2; ks++) {
#pragma unroll
      for (int mt = 0; mt < 4; mt++) {
        f16x8 ak = *(const f16x8*)&Ks[cur][(mt * 16 + l16) * 64 +
                                           (((ks * 4 + quad) ^ (l16 & 7)) << 3)];
        scB[mt][0] = MFMA16(ak, bqB[0][ks], scB[mt][0]);
        scB[mt][1] = MFMA16(ak, bqB[1][ks], scB[mt][1]);
        if (actA) {
          scA[mt][0] = MFMA16(ak, bqA[0][ks], scA[mt][0]);
          scA[mt][1] = MFMA16(ak, bqA[1][ks], scA[mt][1]);
        }
      }
    }

    float alA[2], alB[2];
    softmax_store(scB, mB, lB, alB, qminB, Ps[wid + 4], k0g);
    if (actA) softmax_store(scA, mA, lA, alA, qminA, Ps[wid], k0g);

#pragma unroll
    for (int md = 0; md < 4; md++) {
      oB[md][0] *= alB[0];
      oB[md][1] *= alB[1];
      if (actA) { oA[md][0] *= alA[0]; oA[md][1] *= alA[1]; }
    }

    // ---- PV: shared V^T fragments feed both ----
#pragma unroll
    for (int ks = 0; ks < 2; ks++) {
      f16x8 bpB0 = *(const f16x8*)&Ps[wid + 4][l16 * 72 + ks * 32 + quad * 8];
      f16x8 bpB1 = *(const f16x8*)&Ps[wid + 4][(16 + l16) * 72 + ks * 32 + quad * 8];
      f16x8 bpA0, bpA1;
      if (actA) {
        bpA0 = *(const f16x8*)&Ps[wid][l16 * 72 + ks * 32 + quad * 8];
        bpA1 = *(const f16x8*)&Ps[wid][(16 + l16) * 72 + ks * 32 + quad * 8];
      }
#pragma unroll
      for (int md = 0; md < 4; md++) {
        f16x8 av = *(const f16x8*)&VTs[cur][(md * 16 + l16) * 64 +
                                            (((ks * 4 + quad) ^ (l16 & 7)) << 3)];
        oB[md][0] = MFMA16(av, bpB0, oB[md][0]);
        oB[md][1] = MFMA16(av, bpB1, oB[md][1]);
        if (actA) {
          oA[md][0] = MFMA16(av, bpA0, oA[md][0]);
          oA[md][1] = MFMA16(av, bpA1, oA[md][1]);
        }
      }
    }

    if (pf) stage_KV(nxt, pk0, pk1, pv0, pv1);
    __syncthreads();
  }

  // ---- epilogues: normalize, transpose via per-wave LDS, coalesced store ----
  auto epilogue = [&](float (&l_i)[2], f32x4 (&o)[4][2], int qt) {
#pragma unroll
    for (int nt = 0; nt < 2; nt++) {
      float inv = 1.0f / l_i[nt];
#pragma unroll
      for (int md = 0; md < 4; md++) {
        _Float16 hh[4];
#pragma unroll
        for (int r = 0; r < 4; r++) hh[r] = (_Float16)(o[md][nt][r] * inv);
        *(uint2*)&Ps[wid][(nt * 16 + l16) * 72 + md * 16 + quad * 4] = *(uint2*)hh;
      }
    }
    int r = lane >> 1, ch = (lane & 1) * 32;
    const int qg = qt + wid * 32 + r;
    _Float16* orow = out + (size_t)(b * S_LEN + qg) * DMODEL + h * HD + ch;
#pragma unroll
    for (int i = 0; i < 4; i++)
      *(uint4*)(orow + i * 8) = *(const uint4*)&Ps[wid][r * 72 + ch + i * 8];
  };
  epilogue(lA, oA, qtA);
  epilogue(lB, oB, qtB);
}

// ---------------- launcher ----------------
extern "C" void kernel_launch(void* const* d_in, const int* in_sizes, int n_in,
                              void* d_out, int out_size, void* d_ws, size_t ws_size,
                              hipStream_t stream) {
  const float* x = (const float*)d_in[0];
  const float* w_attn = (const float*)d_in[1];
  const float* b_attn = (const float*)d_in[2];
  const float* w_proj = (const float*)d_in[3];
  const float* b_proj = (const float*)d_in[4];
  float* outp = (float*)d_out;

  char* ws = (char*)d_ws;
  _Float16* x16 = (_Float16*)ws;                         // 16,777,216 B
  _Float16* wTa = (_Float16*)(ws + 16777216);            //  6,291,456 B
  _Float16* wTp = (_Float16*)(ws + 16777216 + 6291456);  //  2,097,152 B
  _Float16* qkv = (_Float16*)(ws + 25165824);            // 50,331,648 B
  _Float16* abuf = (_Float16*)(ws + 75497472);           // 16,777,216 B

  const int nx = BTOT * S_LEN * DMODEL;

  cvt_f32_f16_k<<<8192, 256, 0, stream>>>(x, x16, nx);
  transpose_cvt_k<<<dim3(QKV_LD / 32, DMODEL / 32), dim3(32, 8), 0, stream>>>(
      w_attn, wTa, DMODEL, QKV_LD);
  transpose_cvt_k<<<dim3(DMODEL / 32, DMODEL / 32), dim3(32, 8), 0, stream>>>(
      w_proj, wTp, DMODEL, DMODEL);

  gemm_bt_k<0><<<dim3(QKV_LD / 128, BTOT * S_LEN / 128), 256, 0, stream>>>(
      x16, wTa, b_attn, qkv, BTOT * S_LEN, QKV_LD, DMODEL);

  attn_k<<<dim3(8, BTOT * NHEAD), 256, 0, stream>>>(qkv, abuf);

  gemm_bt_k<1><<<dim3(DMODEL / 128, BTOT * S_LEN / 128), 256, 0, stream>>>(
      abuf, wTp, b_proj, outp, BTOT * S_LEN, DMODEL, DMODEL);
}